// Round 10
// baseline (7482.427 us; speedup 1.0000x reference)
//
#include <hip/hip_runtime.h>
#include <hip/hip_bf16.h>
#include <stdint.h>

#define DD   1024
#define TD   3072
#define DFFN 4096
#define NL   12
#define SS   1040
#define SP   1056          /* padded seq for attention operand arena */
#define BB   8
#define MM   (BB*SS)       /* 8320 */
#define MP   8448          /* M padded to 33*256 for 256-tile GEMM */
#define HH   16
#define NTAIL 16           /* leading tail blocks in attn_staged grid */

typedef float  f32x4  __attribute__((ext_vector_type(4)));
typedef __bf16 bf16x8 __attribute__((ext_vector_type(8)));
typedef unsigned short u16;

union Bf8 { bf16x8 v; u16 s[8]; };

__device__ __forceinline__ u16 f2b(float f) {
  union { float f; unsigned u; } x; x.f = f;
  unsigned r = (x.u + 0x7FFFu + ((x.u >> 16) & 1u)) >> 16;
  return (u16)r;
}

__device__ __forceinline__ f32x4 mfma_bf16(bf16x8 a, bf16x8 b, f32x4 c) {
  return __builtin_amdgcn_mfma_f32_16x16x32_bf16(a, b, c, 0, 0, 0);
}

__device__ __forceinline__ void gload_lds16(const u16* g, u16* l) {
  __builtin_amdgcn_global_load_lds((const __attribute__((address_space(1))) void*)g,
                                   (__attribute__((address_space(3))) void*)l, 16, 0, 0);
}

// ---------------- weight cast+transpose: in (K,N) f32 -> out (N,K) bf16, per layer z ----
__global__ __launch_bounds__(256)
void transpose_cast(const float* __restrict__ in, u16* __restrict__ out, int K, int N) {
  __shared__ float tile[32][33];
  const int n0 = blockIdx.x * 32, k0 = blockIdx.y * 32;
  const size_t lb = (size_t)blockIdx.z * K * N;
  const int tx = threadIdx.x, ty = threadIdx.y;
  for (int j = 0; j < 4; ++j)
    tile[ty + 8*j][tx] = in[lb + (size_t)(k0 + ty + 8*j) * N + n0 + tx];
  __syncthreads();
  for (int j = 0; j < 4; ++j)
    out[lb + (size_t)(n0 + ty + 8*j) * K + k0 + tx] = f2b(tile[tx][ty + 8*j]);
}

// ---------------- LayerNorm: row of 1024, OUTF=0 -> bf16 out, OUTF=1 -> f32 out --------
template<int OUTF>
__global__ __launch_bounds__(256)
void ln_kernel(const float* __restrict__ in, const float* __restrict__ gam,
               const float* __restrict__ bet, u16* __restrict__ outb, float* __restrict__ outf) {
  const int row = blockIdx.x, t = threadIdx.x;
  const float4 v = ((const float4*)(in + (size_t)row * DD))[t];
  float s  = v.x + v.y + v.z + v.w;
  float s2 = v.x*v.x + v.y*v.y + v.z*v.z + v.w*v.w;
  for (int off = 1; off < 64; off <<= 1) { s += __shfl_xor(s, off); s2 += __shfl_xor(s2, off); }
  __shared__ float red[8];
  if ((t & 63) == 0) { red[t >> 6] = s; red[4 + (t >> 6)] = s2; }
  __syncthreads();
  s  = red[0] + red[1] + red[2] + red[3];
  s2 = red[4] + red[5] + red[6] + red[7];
  const float mu = s * (1.0f/1024.0f);
  const float var = s2 * (1.0f/1024.0f) - mu*mu;
  const float rs = rsqrtf(var + 1e-6f);
  const float4 gv = ((const float4*)gam)[t];
  const float4 bv = ((const float4*)bet)[t];
  const float y0 = (v.x - mu)*rs*gv.x + bv.x;
  const float y1 = (v.y - mu)*rs*gv.y + bv.y;
  const float y2 = (v.z - mu)*rs*gv.z + bv.z;
  const float y3 = (v.w - mu)*rs*gv.w + bv.w;
  if (OUTF) {
    float4 o; o.x=y0; o.y=y1; o.z=y2; o.w=y3;
    ((float4*)(outf + (size_t)row * DD))[t] = o;
  } else {
    ushort4 o; o.x=f2b(y0); o.y=f2b(y1); o.z=f2b(y2); o.w=f2b(y3);
    ((ushort4*)(outb + (size_t)row * DD))[t] = o;
  }
}

// ---------------- 128² GEMM (kept for N=1024 shapes): C = A @ Bt^T + bias [+ epi] -----
// EPI 1: gelu, write bf16.  EPI 2: +resid, write f32.
template<int EPI>
__global__ __launch_bounds__(256, 2)
void gemm_bt(const u16* __restrict__ A, const u16* __restrict__ Bt,
             const float* __restrict__ bias, const float* __restrict__ resid,
             float* outF, u16* outB, int N, int K) {
  __shared__ u16 As[128*64];
  __shared__ u16 Bs[128*64];
  const int tid = threadIdx.x;

  const int nwg = gridDim.x * gridDim.y;
  int wgid = blockIdx.y * gridDim.x + blockIdx.x;
  wgid = (wgid & 7) * (nwg >> 3) + (wgid >> 3);
  const int mb = wgid % gridDim.x;
  const int nb = wgid / gridDim.x;
  const int m0 = mb * 128, n0 = nb * 128;

  const int lane = tid & 63, w = tid >> 6;
  const int wr = (w >> 1) * 64, wc = (w & 1) * 64;
  const int c = lane & 15, g = lane >> 4;

  f32x4 acc[4][4];
  for (int i = 0; i < 4; ++i) for (int j = 0; j < 4; ++j) acc[i][j] = f32x4{0.f,0.f,0.f,0.f};

  const int srow = tid >> 3, scg = tid & 7;
  const size_t aoff = (size_t)(m0 + srow) * K + scg * 8;
  const size_t boff = (size_t)(n0 + srow) * K + scg * 8;

  for (int kt = 0; kt < K; kt += 64) {
    for (int it = 0; it < 4; ++it) {
      gload_lds16(A  + aoff + (size_t)it * 32 * K + kt, As + (it*256 + tid) * 8);
      gload_lds16(Bt + boff + (size_t)it * 32 * K + kt, Bs + (it*256 + tid) * 8);
    }
    __syncthreads();
    for (int kk = 0; kk < 2; ++kk) {
      bf16x8 af[4], bfr[4];
      for (int i = 0; i < 4; ++i) af[i]  = *(const bf16x8*)(As + (wr + i*16 + c)*64 + kk*32 + g*8);
      for (int j = 0; j < 4; ++j) bfr[j] = *(const bf16x8*)(Bs + (wc + j*16 + c)*64 + kk*32 + g*8);
      for (int i = 0; i < 4; ++i)
        for (int j = 0; j < 4; ++j)
          acc[i][j] = mfma_bf16(af[i], bfr[j], acc[i][j]);
    }
    __syncthreads();
  }

  for (int j = 0; j < 4; ++j) {
    const int col = n0 + wc + j*16 + c;
    const float bcol = bias[col];
    for (int i = 0; i < 4; ++i) {
      const int row0 = m0 + wr + i*16 + 4*g;
      for (int r = 0; r < 4; ++r) {
        const size_t idx = (size_t)(row0 + r) * N + col;
        const float v = acc[i][j][r] + bcol;
        if (EPI == 1) {
          const float z = 1.5957691216f * (v + 0.044715f * v * v * v);
          const float e = __expf(z);
          outB[idx] = f2b(v * e * __builtin_amdgcn_rcpf(e + 1.0f));
        } else {
          outF[idx] = v + resid[idx];
        }
      }
    }
  }
}

// ---------------- 256² GEMM, counted-vmcnt double-buffer, swizzled LDS ----------------
// 8 waves (2M x 4N), per-wave 128x64 output. A is (MP,K) bf16 (pad rows finite garbage).
// EPI 1: gelu -> outB bf16.  EPI 3: qkv scatter (guarded row<MM).
template<int EPI>
__global__ __launch_bounds__(512, 2)
void gemm256(const u16* __restrict__ A, const u16* __restrict__ Bt,
             const float* __restrict__ bias, u16* __restrict__ outB,
             u16* __restrict__ qb, u16* __restrict__ kb, u16* __restrict__ vtb,
             int N, int K, int MT) {
  __shared__ u16 As[2][256*64];
  __shared__ u16 Bs[2][256*64];
  const int tid = threadIdx.x;

  // bijective XCD swizzle (m204): works for any nwg
  const int nwg = gridDim.x;
  const int q8 = nwg >> 3, r8 = nwg & 7;
  const int xcd = blockIdx.x & 7, bidx = blockIdx.x >> 3;
  const int wgid = (xcd < r8 ? xcd * (q8 + 1) : r8 * (q8 + 1) + (xcd - r8) * q8) + bidx;
  const int mb = wgid % MT, nb = wgid / MT;
  const int m0 = mb * 256, n0 = nb * 256;

  const int lane = tid & 63, w = tid >> 6;
  const int wr = w >> 2, wc = w & 3;           // 2 x 4 wave grid
  const int c = lane & 15, g = lane >> 4;
  const int c7 = c & 7;

  // staging: 512 thr x 16B = 64 rows/round; 4 rounds A + 4 rounds B per K-tile.
  // LDS linear dest; source col-group pre-swizzled by row&7 (involution, G21).
  const int srow = tid >> 3;
  const int sgrp = (tid & 7) ^ (srow & 7);
  const u16* aSrc = A  + (size_t)(m0 + srow) * K + sgrp * 8;
  const u16* bSrc = Bt + (size_t)(n0 + srow) * K + sgrp * 8;

  f32x4 acc[8][4];
#pragma unroll
  for (int i = 0; i < 8; ++i)
#pragma unroll
    for (int j = 0; j < 4; ++j) acc[i][j] = f32x4{0.f,0.f,0.f,0.f};

  const int NT = K >> 6;
#define STAGE256(buf, t) do {                                              \
    _Pragma("unroll")                                                      \
    for (int i_ = 0; i_ < 4; ++i_)                                         \
      gload_lds16(aSrc + ((size_t)i_*64) * K + (size_t)(t)*64, &As[buf][i_*4096 + tid*8]); \
    _Pragma("unroll")                                                      \
    for (int i_ = 0; i_ < 4; ++i_)                                         \
      gload_lds16(bSrc + ((size_t)i_*64) * K + (size_t)(t)*64, &Bs[buf][i_*4096 + tid*8]); \
  } while (0)

  STAGE256(0, 0);
  STAGE256(1, 1);

  for (int t = 0; t < NT; ++t) {
    const int cur = t & 1;
    if (t < NT - 1) asm volatile("s_waitcnt vmcnt(8)" ::: "memory");
    else            asm volatile("s_waitcnt vmcnt(0)" ::: "memory");
    __builtin_amdgcn_s_barrier();
    __builtin_amdgcn_sched_barrier(0);

    const u16* Ac = As[cur];
    const u16* Bc = Bs[cur];

    bf16x8 bfr[4][2];
#pragma unroll
    for (int nf = 0; nf < 4; ++nf)
#pragma unroll
      for (int kk = 0; kk < 2; ++kk) {
        const int row = wc*64 + nf*16 + c;
        const int grp = (kk*4 + g) ^ c7;
        bfr[nf][kk] = *(const bf16x8*)(Bc + row*64 + grp*8);
      }
#pragma unroll
    for (int p = 0; p < 4; ++p) {
      bf16x8 af[2][2];
#pragma unroll
      for (int mi = 0; mi < 2; ++mi)
#pragma unroll
        for (int kk = 0; kk < 2; ++kk) {
          const int row = wr*128 + (p*2 + mi)*16 + c;
          const int grp = (kk*4 + g) ^ c7;
          af[mi][kk] = *(const bf16x8*)(Ac + row*64 + grp*8);
        }
      __builtin_amdgcn_s_setprio(1);
#pragma unroll
      for (int mi = 0; mi < 2; ++mi)
#pragma unroll
        for (int nf = 0; nf < 4; ++nf)
#pragma unroll
          for (int kk = 0; kk < 2; ++kk)
            acc[p*2+mi][nf] = mfma_bf16(af[mi][kk], bfr[nf][kk], acc[p*2+mi][nf]);
      __builtin_amdgcn_s_setprio(0);
    }
    __builtin_amdgcn_sched_barrier(0);
    __builtin_amdgcn_s_barrier();
    if (t + 2 < NT) STAGE256(cur, t + 2);
  }
#undef STAGE256

  // epilogue
#pragma unroll
  for (int nf = 0; nf < 4; ++nf) {
    const int col = n0 + wc*64 + nf*16 + c;
    const float bcol = bias[col];
#pragma unroll
    for (int mf = 0; mf < 8; ++mf) {
      const int row0 = m0 + wr*128 + mf*16 + 4*g;
      if (EPI == 3) {
        if (row0 < MM) {
          const int part = col >> 10;
          const int hh2  = (col >> 6) & 15;
          const int hd   = col & 63;
          const int bb   = (int)((unsigned)row0 / SS);
          const int s0   = row0 - bb * SS;
          const size_t bh = (size_t)(bb * HH + hh2);
          if (part == 2) {
            ushort4 pk;
            pk.x = f2b(acc[mf][nf][0] + bcol);
            pk.y = f2b(acc[mf][nf][1] + bcol);
            pk.z = f2b(acc[mf][nf][2] + bcol);
            pk.w = f2b(acc[mf][nf][3] + bcol);
            *(ushort4*)(vtb + (bh*64 + hd)*SP + s0) = pk;
          } else if (part == 0) {
            for (int r = 0; r < 4; ++r)
              qb[(bh*SP + s0 + r)*64 + hd] = f2b((acc[mf][nf][r] + bcol) * 0.125f);
          } else {
            for (int r = 0; r < 4; ++r)
              kb[(bh*SP + s0 + r)*64 + hd] = f2b(acc[mf][nf][r] + bcol);
          }
        }
      } else {
        for (int r = 0; r < 4; ++r) {
          const float v = acc[mf][nf][r] + bcol;
          const float z = 1.5957691216f * (v + 0.044715f * v * v * v);
          const float e = __expf(z);
          outB[(size_t)(row0 + r) * N + col] = f2b(v * e * __builtin_amdgcn_rcpf(e + 1.0f));
        }
      }
    }
  }
}

// ---------------- staged attention + fused tail (unchanged from r9) -------------------
__global__ __launch_bounds__(512, 8)
void attn_staged(const u16* __restrict__ Qb, const u16* __restrict__ Kb,
                 const u16* __restrict__ VTb, u16* __restrict__ out,
                 const int* __restrict__ npt) {
  __shared__ u16 KV[2][4096];
  __shared__ u16 PT[8][640];
  const int tid = threadIdx.x;
  const int w = tid >> 6, lane = tid & 63;
  const int c = lane & 15, g = lane >> 4;
  const int nin = npt[0];
  u16* pw = PT[w];

  if (blockIdx.x < NTAIL) {
    const int bh = blockIdx.x * 8 + w;
    const int b = bh >> 4, hh = bh & 15;
    const int q0 = 64 * 16;

    bf16x8 aq0, aq1;
    {
      const u16* qp = Qb + ((size_t)bh * SP + q0 + c) * 64 + g * 8;
      aq0 = *(const bf16x8*)qp;
      aq1 = *(const bf16x8*)(qp + 32);
    }

    float m[4], ls[4];
    f32x4 o[4];
    int qrow[4];
    for (int r = 0; r < 4; ++r) { m[r] = -1e30f; ls[r] = 0.f; qrow[r] = q0 + 4*g + r; }
    for (int nd = 0; nd < 4; ++nd) o[nd] = f32x4{0.f,0.f,0.f,0.f};

    for (int kt = 0; kt < 33; ++kt) {
      const int k0 = kt * 32;

      f32x4 s[2];
      {
        const u16* kp0 = Kb + ((size_t)bh * SP + k0 + c) * 64 + g * 8;
        f32x4 z0 = f32x4{0.f,0.f,0.f,0.f};
        z0 = mfma_bf16(aq0, *(const bf16x8*)kp0, z0);
        z0 = mfma_bf16(aq1, *(const bf16x8*)(kp0 + 32), z0);
        s[0] = z0;
        const u16* kp1 = kp0 + 16 * 64;
        f32x4 z1 = f32x4{0.f,0.f,0.f,0.f};
        z1 = mfma_bf16(aq0, *(const bf16x8*)kp1, z1);
        z1 = mfma_bf16(aq1, *(const bf16x8*)(kp1 + 32), z1);
        s[1] = z1;
      }

      for (int jt = 0; jt < 2; ++jt) {
        const int j = k0 + jt*16 + c;
        for (int r = 0; r < 4; ++r) {
          const int q = qrow[r];
          const bool blocked = (j >= SS) || ((q >= nin) && (j >= nin) && (j > q));
          if (blocked) s[jt][r] = -1e30f;
        }
      }

      for (int r = 0; r < 4; ++r) {
        float t = fmaxf(s[0][r], s[1][r]);
        for (int off = 1; off < 16; off <<= 1) t = fmaxf(t, __shfl_xor(t, off));
        const float mn = fmaxf(m[r], t);
        const float al = __expf(m[r] - mn);
        m[r] = mn;
        const float p0 = __expf(s[0][r] - mn);
        const float p1 = __expf(s[1][r] - mn);
        s[0][r] = p0; s[1][r] = p1;
        float ps = p0 + p1;
        for (int off = 1; off < 16; off <<= 1) ps += __shfl_xor(ps, off);
        ls[r] = ls[r] * al + ps;
        for (int nd = 0; nd < 4; ++nd) o[nd][r] *= al;
      }

      for (int jt = 0; jt < 2; ++jt)
        for (int r = 0; r < 4; ++r)
          pw[(4*g + r)*40 + jt*16 + c] = f2b(s[jt][r]);
      __builtin_amdgcn_sched_barrier(0);
      bf16x8 ap = *(const bf16x8*)(pw + c*40 + 8*g);
      __builtin_amdgcn_sched_barrier(0);

      for (int nd = 0; nd < 4; ++nd) {
        const u16* vp = VTb + ((size_t)bh * 64 + nd*16 + c) * SP + k0 + 8*g;
        o[nd] = mfma_bf16(ap, *(const bf16x8*)vp, o[nd]);
      }
    }

    for (int nd = 0; nd < 4; ++nd)
      for (int r = 0; r < 4; ++r) {
        const float v = o[nd][r] / ls[r];
        out[((size_t)b * SS + qrow[r]) * DD + hh*64 + nd*16 + c] = f2b(v);
      }
    return;
  }

  const int sb = blockIdx.x - NTAIL;
  const int bh = sb & 127;
  const int qt = (sb >> 7) * 8 + w;
  const int b = bh >> 4, hh = bh & 15;
  const int q0 = qt * 16;

  const u16* ssrc; int kstr; u16* sdst;
  if (tid < 256) {
    const int row = tid >> 3, col8 = (tid & 7) ^ (row & 7);
    ssrc = Kb + ((size_t)bh * SP + row) * 64 + col8 * 8;
    kstr = 32 * 64;
    sdst = &KV[0][tid * 8];
  } else {
    const int t2 = tid - 256, row = t2 >> 2, col8 = (t2 & 3) ^ (row & 3);
    ssrc = VTb + ((size_t)bh * 64 + row) * SP + col8 * 8;
    kstr = 32;
    sdst = &KV[0][2048 + t2 * 8];
  }
#define STAGE(bufbit, kt) gload_lds16(ssrc + (size_t)(kt) * kstr, sdst + (bufbit) * 4096)

  bf16x8 aq0, aq1;
  {
    const u16* qp = Qb + ((size_t)bh * SP + q0 + c) * 64 + g * 8;
    aq0 = *(const bf16x8*)qp;
    aq1 = *(const bf16x8*)(qp + 32);
  }

  float m[4], ls[4];
  f32x4 o[4];
  int qrow[4];
  for (int r = 0; r < 4; ++r) { m[r] = -1e30f; ls[r] = 0.f; qrow[r] = q0 + 4*g + r; }
  for (int nd = 0; nd < 4; ++nd) o[nd] = f32x4{0.f,0.f,0.f,0.f};

  const bool tile_regs = (q0 + 15) >= nin;
  const int c7 = c & 7, c3 = c & 3;

  STAGE(0, 0);

  for (int kt = 0; kt < 33; ++kt) {
    const int buf = kt & 1;
    __syncthreads();
    if (kt < 32) STAGE(buf ^ 1, kt + 1);
    const u16* Kt = &KV[buf][0];
    const u16* Vt = &KV[buf][2048];
    const int k0 = kt * 32;

    f32x4 s[2];
    {
      bf16x8 k00 = *(const bf16x8*)(Kt + c*64        + ((g    ) ^ c7) * 8);
      bf16x8 k01 = *(const bf16x8*)(Kt + c*64        + ((g + 4) ^ c7) * 8);
      f32x4 z0 = f32x4{0.f,0.f,0.f,0.f};
      z0 = mfma_bf16(aq0, k00, z0);
      z0 = mfma_bf16(aq1, k01, z0);
      s[0] = z0;
      bf16x8 k10 = *(const bf16x8*)(Kt + (c+16)*64   + ((g    ) ^ c7) * 8);
      bf16x8 k11 = *(const bf16x8*)(Kt + (c+16)*64   + ((g + 4) ^ c7) * 8);
      f32x4 z1 = f32x4{0.f,0.f,0.f,0.f};
      z1 = mfma_bf16(aq0, k10, z1);
      z1 = mfma_bf16(aq1, k11, z1);
      s[1] = z1;
    }

    if (tile_regs || (k0 + 31 >= SS)) {
      for (int jt = 0; jt < 2; ++jt) {
        const int j = k0 + jt*16 + c;
        for (int r = 0; r < 4; ++r) {
          const int q = qrow[r];
          const bool blocked = (j >= SS) || ((q >= nin) && (j >= nin) && (j > q));
          if (blocked) s[jt][r] = -1e30f;
        }
      }
    }

    for (int r = 0; r < 4; ++r) {
      float t = fmaxf(s[0][r], s[1][r]);
      for (int off = 1; off < 16; off <<= 1) t = fmaxf(t, __shfl_xor(t, off));
      const float mn = fmaxf(m[r], t);
      const float al = __expf(m[r] - mn);
      m[r] = mn;
      const float p0 = __expf(s[0][r] - mn);
      const float p1 = __expf(s[1][r] - mn);
      s[0][r] = p0; s[1][r] = p1;
      float ps = p0 + p1;
      for (int off = 1; off < 16; off <<= 1) ps += __shfl_xor(ps, off);
      ls[r] = ls[r] * al + ps;
      for (int nd = 0; nd < 4; ++nd) o[nd][r] *= al;
    }

    for (int jt = 0; jt < 2; ++jt)
      for (int r = 0; r < 4; ++r)
        pw[(4*g + r)*40 + jt*16 + c] = f2b(s[jt][r]);
    __builtin_amdgcn_sched_barrier(0);
    bf16x8 ap = *(const bf16x8*)(pw + c*40 + 8*g);
    __builtin_amdgcn_sched_barrier(0);

    for (int nd = 0; nd < 4; ++nd) {
      bf16x8 bv = *(const bf16x8*)(Vt + (nd*16 + c)*32 + ((g ^ c3) * 8));
      o[nd] = mfma_bf16(ap, bv, o[nd]);
    }
  }
#undef STAGE

  for (int nd = 0; nd < 4; ++nd)
    for (int r = 0; r < 4; ++r) {
      const float v = o[nd][r] / ls[r];
      out[((size_t)b * SS + qrow[r]) * DD + hh*64 + nd*16 + c] = f2b(v);
    }
}

// ---------------------------------------------------------------------------------------
extern "C" void kernel_launch(void* const* d_in, const int* in_sizes, int n_in,
                              void* d_out, int out_size, void* d_ws, size_t ws_size,
                              hipStream_t stream) {
  const float* x    = (const float*)d_in[0];
  const int*   npt  = (const int*)  d_in[1];
  const float* ln1g = (const float*)d_in[2];
  const float* ln1b = (const float*)d_in[3];
  const float* wqkv = (const float*)d_in[4];
  const float* bqkv = (const float*)d_in[5];
  const float* wo   = (const float*)d_in[6];
  const float* bo   = (const float*)d_in[7];
  const float* ln2g = (const float*)d_in[8];
  const float* ln2b = (const float*)d_in[9];
  const float* w1   = (const float*)d_in[10];
  const float* b1   = (const float*)d_in[11];
  const float* w2   = (const float*)d_in[12];
  const float* b2   = (const float*)d_in[13];
  const float* lnfg = (const float*)d_in[14];
  const float* lnfb = (const float*)d_in[15];

  char* ws = (char*)d_ws;
  size_t off = 0;
  u16*   wqkvT = (u16*)(ws + off);   off += (size_t)NL*TD*DD*2;
  u16*   woT   = (u16*)(ws + off);   off += (size_t)NL*DD*DD*2;
  u16*   w1T   = (u16*)(ws + off);   off += (size_t)NL*DFFN*DD*2;
  u16*   w2T   = (u16*)(ws + off);   off += (size_t)NL*DD*DFFN*2;
  float* h     = (float*)(ws + off); off += (size_t)MP*DD*4;
  u16*   lnb   = (u16*)(ws + off);   off += (size_t)MP*DD*2;
  u16*   Qb    = (u16*)(ws + off);   off += (size_t)BB*HH*SP*64*2;
  u16*   Kb    = (u16*)(ws + off);   off += (size_t)BB*HH*SP*64*2;
  u16*   VTb   = (u16*)(ws + off);   off += (size_t)BB*HH*64*SP*2;
  u16*   attnO = (u16*)(ws + off);   off += (size_t)MP*DD*2;
  u16*   ffh   = (u16*)(ws + off);   off += (size_t)MP*DFFN*2;

  const dim3 tb(32, 8);
  transpose_cast<<<dim3(TD/32,   DD/32,   NL), tb, 0, stream>>>(wqkv, wqkvT, DD,   TD);
  transpose_cast<<<dim3(DD/32,   DD/32,   NL), tb, 0, stream>>>(wo,   woT,   DD,   DD);
  transpose_cast<<<dim3(DFFN/32, DD/32,   NL), tb, 0, stream>>>(w1,   w1T,   DD,   DFFN);
  transpose_cast<<<dim3(DD/32,   DFFN/32, NL), tb, 0, stream>>>(w2,   w2T,   DFFN, DD);
  hipMemcpyAsync(h, x, (size_t)MM*DD*4, hipMemcpyDeviceToDevice, stream);
  hipMemsetAsync(Qb, 0, (size_t)3*BB*HH*SP*64*2, stream);   // zero Q/K/VT arena (pads)

  for (int l = 0; l < NL; ++l) {
    ln_kernel<0><<<MM, 256, 0, stream>>>(h, ln1g + (size_t)l*DD, ln1b + (size_t)l*DD, lnb, nullptr);
    gemm256<3><<<dim3((MP/256)*(TD/256)), 512, 0, stream>>>(
        lnb, wqkvT + (size_t)l*TD*DD, bqkv + (size_t)l*TD, nullptr,
        Qb, Kb, VTb, TD, DD, MP/256);
    attn_staged<<<dim3(BB*HH*8 + NTAIL), 512, 0, stream>>>(Qb, Kb, VTb, attnO, npt);
    gemm_bt<2><<<dim3(MM/128, DD/128), 256, 0, stream>>>(
        attnO, woT + (size_t)l*DD*DD, bo + (size_t)l*DD, h, h, nullptr, DD, DD);
    ln_kernel<0><<<MM, 256, 0, stream>>>(h, ln2g + (size_t)l*DD, ln2b + (size_t)l*DD, lnb, nullptr);
    gemm256<1><<<dim3((MP/256)*(DFFN/256)), 512, 0, stream>>>(
        lnb, w1T + (size_t)l*DFFN*DD, b1 + (size_t)l*DFFN, ffh,
        nullptr, nullptr, nullptr, DFFN, DD, MP/256);
    gemm_bt<2><<<dim3(MM/128, DD/128), 256, 0, stream>>>(
        ffh, w2T + (size_t)l*DD*DFFN, b2 + (size_t)l*DD, h, h, nullptr, DD, DFFN);
  }
  ln_kernel<1><<<MM, 256, 0, stream>>>(h, lnfg, lnfb, nullptr, (float*)d_out);
}

// Round 11
// 6550.146 us; speedup vs baseline: 1.1423x; 1.1423x over previous
//
#include <hip/hip_runtime.h>
#include <hip/hip_bf16.h>
#include <stdint.h>

#define DD   1024
#define TD   3072
#define DFFN 4096
#define NL   12
#define SS   1040
#define SP   1056          /* padded seq for attention operand arena */
#define BB   8
#define MM   (BB*SS)       /* 8320 */
#define HH   16
#define NTAIL 16           /* leading tail blocks in attn_staged grid */

typedef float  f32x4  __attribute__((ext_vector_type(4)));
typedef __bf16 bf16x8 __attribute__((ext_vector_type(8)));
typedef unsigned short u16;

union Bf8 { bf16x8 v; u16 s[8]; };

__device__ __forceinline__ u16 f2b(float f) {
  union { float f; unsigned u; } x; x.f = f;
  unsigned r = (x.u + 0x7FFFu + ((x.u >> 16) & 1u)) >> 16;
  return (u16)r;
}

__device__ __forceinline__ f32x4 mfma_bf16(bf16x8 a, bf16x8 b, f32x4 c) {
  return __builtin_amdgcn_mfma_f32_16x16x32_bf16(a, b, c, 0, 0, 0);
}

__device__ __forceinline__ void gload_lds16(const u16* g, u16* l) {
  __builtin_amdgcn_global_load_lds((const __attribute__((address_space(1))) void*)g,
                                   (__attribute__((address_space(3))) void*)l, 16, 0, 0);
}

// 16-lane max reduce via DPP (quad_perm xor1, xor2, row_ror:4, row_ror:8) — VALU-speed.
__device__ __forceinline__ float dppmax16(float t) {
  union { float f; int i; } u, v;
  u.f = t;
  v.i = __builtin_amdgcn_update_dpp(0, u.i, 0xB1, 0xF, 0xF, true);   // quad_perm [1,0,3,2]
  u.f = fmaxf(u.f, v.f);
  v.i = __builtin_amdgcn_update_dpp(0, u.i, 0x4E, 0xF, 0xF, true);   // quad_perm [2,3,0,1]
  u.f = fmaxf(u.f, v.f);
  v.i = __builtin_amdgcn_update_dpp(0, u.i, 0x124, 0xF, 0xF, true);  // row_ror:4
  u.f = fmaxf(u.f, v.f);
  v.i = __builtin_amdgcn_update_dpp(0, u.i, 0x128, 0xF, 0xF, true);  // row_ror:8
  u.f = fmaxf(u.f, v.f);
  return u.f;
}

// ---------------- weight cast+transpose: in (K,N) f32 -> out (N,K) bf16, per layer z ----
__global__ __launch_bounds__(256)
void transpose_cast(const float* __restrict__ in, u16* __restrict__ out, int K, int N) {
  __shared__ float tile[32][33];
  const int n0 = blockIdx.x * 32, k0 = blockIdx.y * 32;
  const size_t lb = (size_t)blockIdx.z * K * N;
  const int tx = threadIdx.x, ty = threadIdx.y;
  for (int j = 0; j < 4; ++j)
    tile[ty + 8*j][tx] = in[lb + (size_t)(k0 + ty + 8*j) * N + n0 + tx];
  __syncthreads();
  for (int j = 0; j < 4; ++j)
    out[lb + (size_t)(n0 + ty + 8*j) * K + k0 + tx] = f2b(tile[tx][ty + 8*j]);
}

// ---------------- LayerNorm: row of 1024, OUTF=0 -> bf16 out, OUTF=1 -> f32 out --------
template<int OUTF>
__global__ __launch_bounds__(256)
void ln_kernel(const float* __restrict__ in, const float* __restrict__ gam,
               const float* __restrict__ bet, u16* __restrict__ outb, float* __restrict__ outf) {
  const int row = blockIdx.x, t = threadIdx.x;
  const float4 v = ((const float4*)(in + (size_t)row * DD))[t];
  float s  = v.x + v.y + v.z + v.w;
  float s2 = v.x*v.x + v.y*v.y + v.z*v.z + v.w*v.w;
  for (int off = 1; off < 64; off <<= 1) { s += __shfl_xor(s, off); s2 += __shfl_xor(s2, off); }
  __shared__ float red[8];
  if ((t & 63) == 0) { red[t >> 6] = s; red[4 + (t >> 6)] = s2; }
  __syncthreads();
  s  = red[0] + red[1] + red[2] + red[3];
  s2 = red[4] + red[5] + red[6] + red[7];
  const float mu = s * (1.0f/1024.0f);
  const float var = s2 * (1.0f/1024.0f) - mu*mu;
  const float rs = rsqrtf(var + 1e-6f);
  const float4 gv = ((const float4*)gam)[t];
  const float4 bv = ((const float4*)bet)[t];
  const float y0 = (v.x - mu)*rs*gv.x + bv.x;
  const float y1 = (v.y - mu)*rs*gv.y + bv.y;
  const float y2 = (v.z - mu)*rs*gv.z + bv.z;
  const float y3 = (v.w - mu)*rs*gv.w + bv.w;
  if (OUTF) {
    float4 o; o.x=y0; o.y=y1; o.z=y2; o.w=y3;
    ((float4*)(outf + (size_t)row * DD))[t] = o;
  } else {
    ushort4 o; o.x=f2b(y0); o.y=f2b(y1); o.z=f2b(y2); o.w=f2b(y3);
    ((ushort4*)(outb + (size_t)row * DD))[t] = o;
  }
}

// ---------------- GEMM: C(M,N) = A(M,K)bf16 @ Bt(N,K)bf16^T + bias [+ epi] -------------
// EPI 0: write f32.  EPI 1: gelu, write bf16.  EPI 2: +resid, write f32.
// EPI 3: qkv scatter -> Qb (b,h,s,hd) bf16 *0.125, Kb (b,h,s,hd) bf16, VTb (b,h,hd,s) bf16.
template<int EPI>
__global__ __launch_bounds__(256, 2)
void gemm_bt(const u16* __restrict__ A, const u16* __restrict__ Bt,
             const float* __restrict__ bias, const float* __restrict__ resid,
             float* outF, u16* outB,
             u16* __restrict__ qb, u16* __restrict__ kb, u16* __restrict__ vtb,
             int N, int K) {
  __shared__ u16 As[128*64];
  __shared__ u16 Bs[128*64];
  const int tid = threadIdx.x;

  // XCD-aware bijective swizzle (nwg % 8 == 0 for all our grids), m-fastest decode
  const int nwg = gridDim.x * gridDim.y;
  int wgid = blockIdx.y * gridDim.x + blockIdx.x;
  wgid = (wgid & 7) * (nwg >> 3) + (wgid >> 3);
  const int mb = wgid % gridDim.x;
  const int nb = wgid / gridDim.x;
  const int m0 = mb * 128, n0 = nb * 128;

  const int lane = tid & 63, w = tid >> 6;
  const int wr = (w >> 1) * 64, wc = (w & 1) * 64;
  const int c = lane & 15, g = lane >> 4;

  f32x4 acc[4][4];
  for (int i = 0; i < 4; ++i) for (int j = 0; j < 4; ++j) acc[i][j] = f32x4{0.f,0.f,0.f,0.f};

  const int srow = tid >> 3, scg = tid & 7;
  const size_t aoff = (size_t)(m0 + srow) * K + scg * 8;
  const size_t boff = (size_t)(n0 + srow) * K + scg * 8;

  for (int kt = 0; kt < K; kt += 64) {
    for (int it = 0; it < 4; ++it) {
      gload_lds16(A  + aoff + (size_t)it * 32 * K + kt, As + (it*256 + tid) * 8);
      gload_lds16(Bt + boff + (size_t)it * 32 * K + kt, Bs + (it*256 + tid) * 8);
    }
    __syncthreads();
    for (int kk = 0; kk < 2; ++kk) {
      bf16x8 af[4], bfr[4];
      for (int i = 0; i < 4; ++i) af[i]  = *(const bf16x8*)(As + (wr + i*16 + c)*64 + kk*32 + g*8);
      for (int j = 0; j < 4; ++j) bfr[j] = *(const bf16x8*)(Bs + (wc + j*16 + c)*64 + kk*32 + g*8);
      for (int i = 0; i < 4; ++i)
        for (int j = 0; j < 4; ++j)
          acc[i][j] = mfma_bf16(af[i], bfr[j], acc[i][j]);
    }
    __syncthreads();
  }

  for (int j = 0; j < 4; ++j) {
    const int col = n0 + wc + j*16 + c;
    const float bcol = bias[col];
    for (int i = 0; i < 4; ++i) {
      const int row0 = m0 + wr + i*16 + 4*g;
      if (EPI == 3) {
        const int part = col >> 10;
        const int hh2  = (col >> 6) & 15;
        const int hd   = col & 63;
        const int bb   = (int)((unsigned)row0 / SS);
        const int s0   = row0 - bb * SS;          // 4-aligned; never crosses batch
        const size_t bh = (size_t)(bb * HH + hh2);
        if (part == 2) {
          ushort4 pk;
          pk.x = f2b(acc[i][j][0] + bcol);
          pk.y = f2b(acc[i][j][1] + bcol);
          pk.z = f2b(acc[i][j][2] + bcol);
          pk.w = f2b(acc[i][j][3] + bcol);
          *(ushort4*)(vtb + (bh*64 + hd)*SP + s0) = pk;
        } else if (part == 0) {
          for (int r = 0; r < 4; ++r)
            qb[(bh*SP + s0 + r)*64 + hd] = f2b((acc[i][j][r] + bcol) * 0.125f);
        } else {
          for (int r = 0; r < 4; ++r)
            kb[(bh*SP + s0 + r)*64 + hd] = f2b(acc[i][j][r] + bcol);
        }
      } else {
        for (int r = 0; r < 4; ++r) {
          const size_t idx = (size_t)(row0 + r) * N + col;
          const float v = acc[i][j][r] + bcol;
          if (EPI == 0) {
            outF[idx] = v;
          } else if (EPI == 1) {
            // tanh-gelu == v * sigmoid(1.5957691*(v + 0.044715 v^3))
            const float z = 1.5957691216f * (v + 0.044715f * v * v * v);
            const float e = __expf(z);
            outB[idx] = f2b(v * e * __builtin_amdgcn_rcpf(e + 1.0f));
          } else {
            outF[idx] = v + resid[idx];
          }
        }
      }
    }
  }
}

// ---------------- staged attention + fused tail --------------------------------------
// Blocks [0, NTAIL): tail path — wave w handles bh = blockIdx*8+w, q-tile 64, direct loads.
// Blocks [NTAIL, NTAIL+1024): staged path — sb = blockIdx-NTAIL.
//   XCD-grouped: bh = sb & 127, qt = (sb>>7)*8 + w (8 blocks per bh land on one XCD).
// Staged-path softmax: DPP max-reduce; ls accumulated via 5th PV MFMA against a register
// ones-fragment (column 0), no sum-shuffles.
__global__ __launch_bounds__(512, 8)
void attn_staged(const u16* __restrict__ Qb, const u16* __restrict__ Kb,
                 const u16* __restrict__ VTb, u16* __restrict__ out,
                 const int* __restrict__ npt) {
  __shared__ u16 KV[2][4096];       // per buf: [0..2048) K tile, [2048..4096) V tile
  __shared__ u16 PT[8][640];        // per-wave P^T, 16 rows x 40 u16 (bf16)
  const int tid = threadIdx.x;
  const int w = tid >> 6, lane = tid & 63;
  const int c = lane & 15, g = lane >> 4;
  const int nin = npt[0];
  u16* pw = PT[w];

  if (blockIdx.x < NTAIL) {
    // ---------------- tail path: q-tile 64, direct global loads (r9 body) -------------
    const int bh = blockIdx.x * 8 + w;
    const int b = bh >> 4, hh = bh & 15;
    const int q0 = 64 * 16;

    bf16x8 aq0, aq1;
    {
      const u16* qp = Qb + ((size_t)bh * SP + q0 + c) * 64 + g * 8;
      aq0 = *(const bf16x8*)qp;
      aq1 = *(const bf16x8*)(qp + 32);
    }

    float m[4], ls[4];
    f32x4 o[4];
    int qrow[4];
    for (int r = 0; r < 4; ++r) { m[r] = -1e30f; ls[r] = 0.f; qrow[r] = q0 + 4*g + r; }
    for (int nd = 0; nd < 4; ++nd) o[nd] = f32x4{0.f,0.f,0.f,0.f};

    for (int kt = 0; kt < 33; ++kt) {
      const int k0 = kt * 32;

      f32x4 s[2];
      {
        const u16* kp0 = Kb + ((size_t)bh * SP + k0 + c) * 64 + g * 8;
        f32x4 z0 = f32x4{0.f,0.f,0.f,0.f};
        z0 = mfma_bf16(aq0, *(const bf16x8*)kp0, z0);
        z0 = mfma_bf16(aq1, *(const bf16x8*)(kp0 + 32), z0);
        s[0] = z0;
        const u16* kp1 = kp0 + 16 * 64;
        f32x4 z1 = f32x4{0.f,0.f,0.f,0.f};
        z1 = mfma_bf16(aq0, *(const bf16x8*)kp1, z1);
        z1 = mfma_bf16(aq1, *(const bf16x8*)(kp1 + 32), z1);
        s[1] = z1;
      }

      for (int jt = 0; jt < 2; ++jt) {
        const int j = k0 + jt*16 + c;
        for (int r = 0; r < 4; ++r) {
          const int q = qrow[r];
          const bool blocked = (j >= SS) || ((q >= nin) && (j >= nin) && (j > q));
          if (blocked) s[jt][r] = -1e30f;
        }
      }

      for (int r = 0; r < 4; ++r) {
        float t = fmaxf(s[0][r], s[1][r]);
        for (int off = 1; off < 16; off <<= 1) t = fmaxf(t, __shfl_xor(t, off));
        const float mn = fmaxf(m[r], t);
        const float al = __expf(m[r] - mn);
        m[r] = mn;
        const float p0 = __expf(s[0][r] - mn);
        const float p1 = __expf(s[1][r] - mn);
        s[0][r] = p0; s[1][r] = p1;
        float ps = p0 + p1;
        for (int off = 1; off < 16; off <<= 1) ps += __shfl_xor(ps, off);
        ls[r] = ls[r] * al + ps;
        for (int nd = 0; nd < 4; ++nd) o[nd][r] *= al;
      }

      for (int jt = 0; jt < 2; ++jt)
        for (int r = 0; r < 4; ++r)
          pw[(4*g + r)*40 + jt*16 + c] = f2b(s[jt][r]);
      __builtin_amdgcn_sched_barrier(0);
      bf16x8 ap = *(const bf16x8*)(pw + c*40 + 8*g);
      __builtin_amdgcn_sched_barrier(0);

      for (int nd = 0; nd < 4; ++nd) {
        const u16* vp = VTb + ((size_t)bh * 64 + nd*16 + c) * SP + k0 + 8*g;
        o[nd] = mfma_bf16(ap, *(const bf16x8*)vp, o[nd]);
      }
    }

    for (int nd = 0; nd < 4; ++nd)
      for (int r = 0; r < 4; ++r) {
        const float v = o[nd][r] / ls[r];
        out[((size_t)b * SS + qrow[r]) * DD + hh*64 + nd*16 + c] = f2b(v);
      }
    return;
  }

  // ---------------- staged path (XCD-grouped bh mapping) ----------------
  const int sb = blockIdx.x - NTAIL;
  const int bh = sb & 127;
  const int qt = (sb >> 7) * 8 + w;
  const int b = bh >> 4, hh = bh & 15;
  const int q0 = qt * 16;

  // staging assignment: threads 0-255 stage K (16B each), 256-511 stage V (16B each)
  const u16* ssrc; int kstr; u16* sdst;
  if (tid < 256) {
    const int row = tid >> 3, col8 = (tid & 7) ^ (row & 7);
    ssrc = Kb + ((size_t)bh * SP + row) * 64 + col8 * 8;
    kstr = 32 * 64;
    sdst = &KV[0][tid * 8];
  } else {
    const int t2 = tid - 256, row = t2 >> 2, col8 = (t2 & 3) ^ (row & 3);
    ssrc = VTb + ((size_t)bh * 64 + row) * SP + col8 * 8;
    kstr = 32;
    sdst = &KV[0][2048 + t2 * 8];
  }
#define STAGE(bufbit, kt) gload_lds16(ssrc + (size_t)(kt) * kstr, sdst + (bufbit) * 4096)

  bf16x8 aq0, aq1;
  {
    const u16* qp = Qb + ((size_t)bh * SP + q0 + c) * 64 + g * 8;
    aq0 = *(const bf16x8*)qp;
    aq1 = *(const bf16x8*)(qp + 32);
  }

  // register ones-fragment: B[k][col]=1 for col==0 -> lanes with c==0 hold 1.0
  Bf8 onesf;
  for (int i = 0; i < 8; ++i) onesf.s[i] = (c == 0) ? (u16)0x3F80 : (u16)0;

  float m[4];
  f32x4 o[5];                        // o[4] = ls accumulator (column 0)
  int qrow[4];
  for (int r = 0; r < 4; ++r) { m[r] = -1e30f; qrow[r] = q0 + 4*g + r; }
  for (int nd = 0; nd < 5; ++nd) o[nd] = f32x4{0.f,0.f,0.f,0.f};

  const bool tile_regs = (q0 + 15) >= nin;
  const int c7 = c & 7, c3 = c & 3;

  STAGE(0, 0);

  for (int kt = 0; kt < 33; ++kt) {
    const int buf = kt & 1;
    __syncthreads();                   // buf staged (drains vmcnt) + prior-buf reads done
    if (kt < 32) STAGE(buf ^ 1, kt + 1);
    const u16* Kt = &KV[buf][0];
    const u16* Vt = &KV[buf][2048];
    const int k0 = kt * 32;

    f32x4 s[2];
    {
      bf16x8 k00 = *(const bf16x8*)(Kt + c*64        + ((g    ) ^ c7) * 8);
      bf16x8 k01 = *(const bf16x8*)(Kt + c*64        + ((g + 4) ^ c7) * 8);
      f32x4 z0 = f32x4{0.f,0.f,0.f,0.f};
      z0 = mfma_bf16(aq0, k00, z0);
      z0 = mfma_bf16(aq1, k01, z0);
      s[0] = z0;
      bf16x8 k10 = *(const bf16x8*)(Kt + (c+16)*64   + ((g    ) ^ c7) * 8);
      bf16x8 k11 = *(const bf16x8*)(Kt + (c+16)*64   + ((g + 4) ^ c7) * 8);
      f32x4 z1 = f32x4{0.f,0.f,0.f,0.f};
      z1 = mfma_bf16(aq0, k10, z1);
      z1 = mfma_bf16(aq1, k11, z1);
      s[1] = z1;
    }

    if (tile_regs || (k0 + 31 >= SS)) {
      for (int jt = 0; jt < 2; ++jt) {
        const int j = k0 + jt*16 + c;
        for (int r = 0; r < 4; ++r) {
          const int q = qrow[r];
          const bool blocked = (j >= SS) || ((q >= nin) && (j >= nin) && (j > q));
          if (blocked) s[jt][r] = -1e30f;
        }
      }
    }

    for (int r = 0; r < 4; ++r) {
      const float t = dppmax16(fmaxf(s[0][r], s[1][r]));
      const float mn = fmaxf(m[r], t);
      const float al = __expf(m[r] - mn);
      m[r] = mn;
      for (int nd = 0; nd < 5; ++nd) o[nd][r] *= al;
      s[0][r] = __expf(s[0][r] - mn);
      s[1][r] = __expf(s[1][r] - mn);
    }

    // P^T into per-wave LDS as bf16 (in-wave DS ordering; pin program order)
    for (int jt = 0; jt < 2; ++jt)
      for (int r = 0; r < 4; ++r)
        pw[(4*g + r)*40 + jt*16 + c] = f2b(s[jt][r]);
    __builtin_amdgcn_sched_barrier(0);
    bf16x8 ap = *(const bf16x8*)(pw + c*40 + 8*g);
    __builtin_amdgcn_sched_barrier(0);

    for (int nd = 0; nd < 4; ++nd) {
      bf16x8 bv = *(const bf16x8*)(Vt + (nd*16 + c)*32 + ((g ^ c3) * 8));
      o[nd] = mfma_bf16(ap, bv, o[nd]);
    }
    o[4] = mfma_bf16(ap, onesf.v, o[4]);   // ls accumulates in column 0
  }
#undef STAGE

  float rls[4];
  for (int r = 0; r < 4; ++r)
    rls[r] = 1.0f / __shfl(o[4][r], lane & 48);   // broadcast ls from c==0 lane of group
  for (int nd = 0; nd < 4; ++nd)
    for (int r = 0; r < 4; ++r)
      out[((size_t)b * SS + qrow[r]) * DD + hh*64 + nd*16 + c] = f2b(o[nd][r] * rls[r]);
}

// ---------------------------------------------------------------------------------------
extern "C" void kernel_launch(void* const* d_in, const int* in_sizes, int n_in,
                              void* d_out, int out_size, void* d_ws, size_t ws_size,
                              hipStream_t stream) {
  const float* x    = (const float*)d_in[0];
  const int*   npt  = (const int*)  d_in[1];
  const float* ln1g = (const float*)d_in[2];
  const float* ln1b = (const float*)d_in[3];
  const float* wqkv = (const float*)d_in[4];
  const float* bqkv = (const float*)d_in[5];
  const float* wo   = (const float*)d_in[6];
  const float* bo   = (const float*)d_in[7];
  const float* ln2g = (const float*)d_in[8];
  const float* ln2b = (const float*)d_in[9];
  const float* w1   = (const float*)d_in[10];
  const float* b1   = (const float*)d_in[11];
  const float* w2   = (const float*)d_in[12];
  const float* b2   = (const float*)d_in[13];
  const float* lnfg = (const float*)d_in[14];
  const float* lnfb = (const float*)d_in[15];

  char* ws = (char*)d_ws;
  size_t off = 0;
  u16*   wqkvT = (u16*)(ws + off);   off += (size_t)NL*TD*DD*2;
  u16*   woT   = (u16*)(ws + off);   off += (size_t)NL*DD*DD*2;
  u16*   w1T   = (u16*)(ws + off);   off += (size_t)NL*DFFN*DD*2;
  u16*   w2T   = (u16*)(ws + off);   off += (size_t)NL*DD*DFFN*2;
  float* h     = (float*)(ws + off); off += (size_t)MM*DD*4;
  u16*   lnb   = (u16*)(ws + off);   off += (size_t)MM*DD*2;
  u16*   Qb    = (u16*)(ws + off);   off += (size_t)BB*HH*SP*64*2;
  u16*   Kb    = (u16*)(ws + off);   off += (size_t)BB*HH*SP*64*2;
  u16*   VTb   = (u16*)(ws + off);   off += (size_t)BB*HH*64*SP*2;
  u16*   attnO = (u16*)(ws + off);   off += (size_t)MM*DD*2;
  u16*   ffh   = (u16*)(ws + off);   off += (size_t)MM*DFFN*2;

  const dim3 tb(32, 8);
  transpose_cast<<<dim3(TD/32,   DD/32,   NL), tb, 0, stream>>>(wqkv, wqkvT, DD,   TD);
  transpose_cast<<<dim3(DD/32,   DD/32,   NL), tb, 0, stream>>>(wo,   woT,   DD,   DD);
  transpose_cast<<<dim3(DFFN/32, DD/32,   NL), tb, 0, stream>>>(w1,   w1T,   DD,   DFFN);
  transpose_cast<<<dim3(DD/32,   DFFN/32, NL), tb, 0, stream>>>(w2,   w2T,   DFFN, DD);
  hipMemcpyAsync(h, x, (size_t)MM*DD*4, hipMemcpyDeviceToDevice, stream);
  hipMemsetAsync(Qb, 0, (size_t)3*BB*HH*SP*64*2, stream);   // zero Q/K/VT arena (pads)

  for (int l = 0; l < NL; ++l) {
    ln_kernel<0><<<MM, 256, 0, stream>>>(h, ln1g + (size_t)l*DD, ln1b + (size_t)l*DD, lnb, nullptr);
    gemm_bt<3><<<dim3(MM/128, TD/128), 256, 0, stream>>>(
        lnb, wqkvT + (size_t)l*TD*DD, bqkv + (size_t)l*TD, nullptr, nullptr, nullptr,
        Qb, Kb, VTb, TD, DD);
    attn_staged<<<dim3(BB*HH*8 + NTAIL), 512, 0, stream>>>(Qb, Kb, VTb, attnO, npt);
    gemm_bt<2><<<dim3(MM/128, DD/128), 256, 0, stream>>>(
        attnO, woT + (size_t)l*DD*DD, bo + (size_t)l*DD, h, h, nullptr,
        nullptr, nullptr, nullptr, DD, DD);
    ln_kernel<0><<<MM, 256, 0, stream>>>(h, ln2g + (size_t)l*DD, ln2b + (size_t)l*DD, lnb, nullptr);
    gemm_bt<1><<<dim3(MM/128, DFFN/128), 256, 0, stream>>>(
        lnb, w1T + (size_t)l*DFFN*DD, b1 + (size_t)l*DFFN, nullptr, nullptr, ffh,
        nullptr, nullptr, nullptr, DFFN, DD);
    gemm_bt<2><<<dim3(MM/128, DD/128), 256, 0, stream>>>(
        ffh, w2T + (size_t)l*DD*DFFN, b2 + (size_t)l*DD, h, h, nullptr,
        nullptr, nullptr, nullptr, DD, DFFN);
  }
  ln_kernel<1><<<MM, 256, 0, stream>>>(h, lnfg, lnfb, nullptr, (float*)d_out);
}